// Round 3
// baseline (429.829 us; speedup 1.0000x reference)
//
#include <hip/hip_runtime.h>

#define BLK 256

constexpr int Bn = 4, Cn = 3, Hn = 1024, Wn = 1024;
constexpr int HW   = Hn * Wn;        // 1<<20
constexpr int BHW  = Bn * HW;        // 4,194,304
constexpr int BCHW = Bn * Cn * HW;   // 12,582,912
constexpr int MAX_ITERS = 4;

// dest-tile ownership splat
constexpr int TS  = 64;              // dest tile side
constexpr int Mg  = 24;              // source window margin
constexpr int WND = TS + 2 * Mg;     // 112
constexpr int NW  = WND * WND;       // 12544
constexpr float FMAX = 23.0f;        // = Mg-1; owner handles |f|<=FMAX exactly

// ---------------- owner splat: no global atomics ----------------
// Each block owns a 64x64 dest tile; scans 112x112 source window; corners
// landing in the tile accumulate via LDS atomics; tile flushed with plain
// coalesced stores (exclusive writer per dest pixel). |flow|>FMAX excluded
// here and handled by splat_fallback (exact complement predicate).
// 1024 threads + software-pipelined loads: latency-bound fix (R2 counters:
// VALUBusy 7.5%, HBM 7%, occ 41% -> nothing saturated, pure vmcnt stalls).
#define STAGE(ii, F, V0, V1, V2, PX, PY, VAL)                                 \
    {   VAL = false;                                                          \
        if ((ii) < NW) {                                                      \
            int wy_ = (ii) / WND;                                             \
            int wx_ = (ii) - wy_ * WND;                                       \
            PY = ty - Mg + wy_;                                               \
            PX = tx - Mg + wx_;                                               \
            if ((unsigned)PY < (unsigned)Hn && (unsigned)PX < (unsigned)Wn) { \
                int p_ = (PY << 10) + PX;                                     \
                F  = flb[p_];                                                 \
                V0 = imb[p_];                                                 \
                V1 = imb[HW + p_];                                            \
                V2 = imb[2 * HW + p_];                                        \
                VAL = true;                                                   \
            }                                                                 \
        }                                                                     \
    }

__global__ __launch_bounds__(1024, 8) void splat_owner(
    const float* __restrict__ im0, const float* __restrict__ flow,
    float* __restrict__ acc, float* __restrict__ wacc)
{
    __shared__ float s[4][TS * TS];   // c0,c1,c2,w : 64 KiB -> 2 blocks/CU
    const int bid  = blockIdx.x;
    const int b    = bid >> 8;        // 256 tiles per batch (16x16)
    const int tile = bid & 255;
    const int ty   = (tile >> 4) * TS;
    const int tx   = (tile & 15) * TS;

    for (int i = threadIdx.x; i < TS * TS; i += 1024) {
        s[0][i] = 0.f; s[1][i] = 0.f; s[2][i] = 0.f; s[3][i] = 0.f;
    }
    __syncthreads();

    const float*  imb = im0 + (size_t)b * Cn * HW;
    const float2* flb = reinterpret_cast<const float2*>(flow) + (size_t)b * HW;

    int i = threadIdx.x;
    float2 fA; float a0, a1, a2; int axp, ayp; bool avalid;
    STAGE(i, fA, a0, a1, a2, axp, ayp, avalid);

    while (i < NW) {
        int ni = i + 1024;
        // prefetch next iteration's 4 loads before touching this one's data
        float2 fB; float b0, b1, b2; int bxp, byp; bool bvalid;
        STAGE(ni, fB, b0, b1, b2, bxp, byp, bvalid);

        if (avalid && fabsf(fA.x) <= FMAX && fabsf(fA.y) <= FMAX) {
            float X = (float)axp + fA.x;
            float Y = (float)ayp + fA.y;
            float x0 = floorf(X), y0 = floorf(Y);
#pragma unroll
            for (int cy = 0; cy < 2; ++cy) {
#pragma unroll
                for (int cx = 0; cx < 2; ++cx) {
                    float xi = x0 + (float)cx;
                    float yi = y0 + (float)cy;
                    int lx = (int)xi - tx;
                    int ly = (int)yi - ty;
                    if ((unsigned)lx >= (unsigned)TS || (unsigned)ly >= (unsigned)TS) continue;
                    // weight arithmetic bitwise-identical to reference (hole mask!)
                    float w = (1.f - fabsf(X - xi)) * (1.f - fabsf(Y - yi));
                    int c = ly * TS + lx;
                    atomicAdd(&s[0][c], a0 * w);
                    atomicAdd(&s[1][c], a1 * w);
                    atomicAdd(&s[2][c], a2 * w);
                    atomicAdd(&s[3][c], w);
                }
            }
        }
        i = ni;
        fA = fB; a0 = b0; a1 = b1; a2 = b2; axp = bxp; ayp = byp; avalid = bvalid;
    }
    __syncthreads();

    float* accb = acc + (size_t)b * Cn * HW;
    float* wb   = wacc + (size_t)b * HW;
    for (int i2 = threadIdx.x; i2 < TS * TS; i2 += 1024) {
        int ly = i2 >> 6, lx = i2 & 63;
        int p = ((ty + ly) << 10) + tx + lx;
        accb[p]          = s[0][i2];
        accb[HW + p]     = s[1][i2];
        accb[2 * HW + p] = s[2][i2];
        wb[p]            = s[3][i2];
    }
}

// ------- fallback: the rare |flow|>FMAX pixels, scattered atomics -------
__global__ __launch_bounds__(BLK) void splat_fallback(
    const float* __restrict__ im0, const float* __restrict__ flow,
    float* __restrict__ acc, float* __restrict__ wacc)
{
    int idx = blockIdx.x * BLK + threadIdx.x;
    if (idx >= BHW) return;
    float2 f = reinterpret_cast<const float2*>(flow)[idx];
    if (fabsf(f.x) <= FMAX && fabsf(f.y) <= FMAX) return;  // owner handled it

    int b = idx >> 20;
    int p = idx & (HW - 1);
    int y = p >> 10;
    int x = p & (Wn - 1);
    float X = (float)x + f.x;
    float Y = (float)y + f.y;
    float x0 = floorf(X), y0 = floorf(Y);
    float v0 = im0[(b * Cn + 0) * HW + p];
    float v1 = im0[(b * Cn + 1) * HW + p];
    float v2 = im0[(b * Cn + 2) * HW + p];
#pragma unroll
    for (int cy = 0; cy < 2; ++cy) {
#pragma unroll
        for (int cx = 0; cx < 2; ++cx) {
            float xi = x0 + (float)cx;
            float yi = y0 + (float)cy;
            if (xi < 0.f || xi > (float)(Wn - 1) ||
                yi < 0.f || yi > (float)(Hn - 1)) continue;
            float w = (1.f - fabsf(X - xi)) * (1.f - fabsf(Y - yi));
            int di = (int)yi * Wn + (int)xi;
            atomicAdd(&wacc[b * HW + di], w);
            atomicAdd(&acc[(b * Cn + 0) * HW + di], v0 * w);
            atomicAdd(&acc[(b * Cn + 1) * HW + di], v1 * w);
            atomicAdd(&acc[(b * Cn + 2) * HW + di], v2 * w);
        }
    }
}

// ------- infill iteration: dst = where(hole, gather(src,flowback), src) -----
__global__ __launch_bounds__(BLK) void infill_kernel(
    const float* __restrict__ src, const float* __restrict__ wacc,
    const float* __restrict__ flowback, float* __restrict__ dst,
    const int* __restrict__ n_iter, int iter)
{
    int n = *n_iter; if (n > MAX_ITERS) n = MAX_ITERS;
    if (iter >= n) return;

    int idx = blockIdx.x * BLK + threadIdx.x;
    if (idx >= BHW) return;
    int b = idx >> 20;
    int p = idx & (HW - 1);

    const float* sb = src + (size_t)b * Cn * HW;
    float o0, o1, o2;
    float wv = wacc[idx];
    if (wv != 0.f) {
        o0 = sb[p];
        o1 = sb[HW + p];
        o2 = sb[2 * HW + p];
    } else {
        int y = p >> 10, x = p & (Wn - 1);
        float2 f = reinterpret_cast<const float2*>(flowback)[idx];
        float X = (float)x + f.x;
        float Y = (float)y + f.y;
        float x0 = floorf(X), y0 = floorf(Y);
        o0 = o1 = o2 = 0.f;
#pragma unroll
        for (int cy = 0; cy < 2; ++cy) {
#pragma unroll
            for (int cx = 0; cx < 2; ++cx) {
                float xi = x0 + (float)cx;
                float yi = y0 + (float)cy;
                if (xi < 0.f || xi > (float)(Wn - 1) ||
                    yi < 0.f || yi > (float)(Hn - 1)) continue;
                float w = (1.f - fabsf(X - xi)) * (1.f - fabsf(Y - yi));
                int gi = (int)yi * Wn + (int)xi;
                o0 += sb[gi] * w;
                o1 += sb[HW + gi] * w;
                o2 += sb[2 * HW + gi] * w;
            }
        }
    }
    float* db = dst + (size_t)b * Cn * HW;
    db[p]          = o0;
    db[HW + p]     = o1;
    db[2 * HW + p] = o2;
}

// ------- if iteration count even (incl. 0), result sits in acc: copy out -----
__global__ __launch_bounds__(BLK) void copy_even_kernel(
    const float* __restrict__ A, float* __restrict__ dst,
    const int* __restrict__ n_iter)
{
    int n = *n_iter; if (n > MAX_ITERS) n = MAX_ITERS;
    if (n & 1) return;   // odd: result already in dst
    int i = blockIdx.x * BLK + threadIdx.x;
    if (i < BCHW) dst[i] = A[i];
}

extern "C" void kernel_launch(void* const* d_in, const int* in_sizes, int n_in,
                              void* d_out, int out_size, void* d_ws, size_t ws_size,
                              hipStream_t stream)
{
    const float* im0      = (const float*)d_in[0];
    const float* flow     = (const float*)d_in[1];
    const float* flowback = (const float*)d_in[2];
    const int*   n_iter   = (const int*)d_in[3];
    float* out  = (float*)d_out;
    float* acc  = (float*)d_ws;          // BCHW floats
    float* wacc = acc + BCHW;            // BHW floats

    // owner splat writes every acc/wacc element -> no memset needed
    int grid_owner = Bn * 256;           // 16x16 tiles of 64x64 per batch
    splat_owner<<<grid_owner, 1024, 0, stream>>>(im0, flow, acc, wacc);

    int grid = (BHW + BLK - 1) / BLK;
    splat_fallback<<<grid, BLK, 0, stream>>>(im0, flow, acc, wacc);

    // ping-pong: iter 0: acc->out, iter 1: out->acc, ...
    for (int i = 0; i < MAX_ITERS; ++i) {
        const float* s = (i % 2 == 0) ? acc : out;
        float*       d = (i % 2 == 0) ? out : acc;
        infill_kernel<<<grid, BLK, 0, stream>>>(s, wacc, flowback, d, n_iter, i);
    }

    int grid2 = (BCHW + BLK - 1) / BLK;
    copy_even_kernel<<<grid2, BLK, 0, stream>>>(acc, out, n_iter);
}

// Round 4
// 139.243 us; speedup vs baseline: 3.0869x; 3.0869x over previous
//
#include <hip/hip_runtime.h>

#define BLK 256

constexpr int Bn = 4, Cn = 3, Hn = 1024, Wn = 1024;
constexpr int HW   = Hn * Wn;        // 1<<20
constexpr int BHW  = Bn * HW;        // 4,194,304
constexpr int BCHW = Bn * Cn * HW;   // 12,582,912
constexpr int MAX_ITERS = 4;

// dest-tile ownership splat
constexpr int TS  = 64;              // dest tile side
constexpr int Mg  = 24;              // source window margin
constexpr int WND = TS + 2 * Mg;     // 112
constexpr int NW  = WND * WND;       // 12544
constexpr float FMAX = 23.0f;        // = Mg-1; owner handles |f|<=FMAX exactly

// fixed-point accumulation scale (R3 post-mortem: LDS f32 atomics appear
// per-lane serialized ~3.2cy; switch channels to i32 ds_add + drop the w-plane
// atomic entirely -- hole mask only needs "any event with w!=0" (all w>=0),
// which an idempotent plain LDS write provides)
constexpr float SCALE = 2097152.0f;        // 2^21
constexpr float INVSC = 4.76837158203125e-07f;  // 2^-21 exact

#define STAGE(ii, F, V0, V1, V2, PX, PY, VAL)                                 \
    {   VAL = false;                                                          \
        if ((ii) < NW) {                                                      \
            int wy_ = (ii) / WND;                                             \
            int wx_ = (ii) - wy_ * WND;                                       \
            PY = ty - Mg + wy_;                                               \
            PX = tx - Mg + wx_;                                               \
            if ((unsigned)PY < (unsigned)Hn && (unsigned)PX < (unsigned)Wn) { \
                int p_ = (PY << 10) + PX;                                     \
                F  = flb[p_];                                                 \
                V0 = imb[p_];                                                 \
                V1 = imb[HW + p_];                                            \
                V2 = imb[2 * HW + p_];                                        \
                VAL = true;                                                   \
            }                                                                 \
        }                                                                     \
    }

__global__ __launch_bounds__(1024, 8) void splat_owner(
    const float* __restrict__ im0, const float* __restrict__ flow,
    float* __restrict__ acc, float* __restrict__ wacc)
{
    __shared__ int s_acc[3][TS * TS];   // fixed-point channel accumulators
    __shared__ int s_flag[TS * TS];     // 1 iff any event with w != 0
    const int bid  = blockIdx.x;
    const int b    = bid >> 8;        // 256 tiles per batch (16x16)
    const int tile = bid & 255;
    const int ty   = (tile >> 4) * TS;
    const int tx   = (tile & 15) * TS;

    for (int i = threadIdx.x; i < TS * TS; i += 1024) {
        s_acc[0][i] = 0; s_acc[1][i] = 0; s_acc[2][i] = 0; s_flag[i] = 0;
    }
    __syncthreads();

    const float*  imb = im0 + (size_t)b * Cn * HW;
    const float2* flb = reinterpret_cast<const float2*>(flow) + (size_t)b * HW;

    int i = threadIdx.x;
    float2 fA; float a0, a1, a2; int axp, ayp; bool avalid;
    STAGE(i, fA, a0, a1, a2, axp, ayp, avalid);

    while (i < NW) {
        int ni = i + 1024;
        // prefetch next iteration's 4 loads before touching this one's data
        float2 fB; float b0, b1, b2; int bxp, byp; bool bvalid;
        STAGE(ni, fB, b0, b1, b2, bxp, byp, bvalid);

        if (avalid && fabsf(fA.x) <= FMAX && fabsf(fA.y) <= FMAX) {
            float X = (float)axp + fA.x;
            float Y = (float)ayp + fA.y;
            float x0 = floorf(X), y0 = floorf(Y);
            float sv0 = a0 * SCALE, sv1 = a1 * SCALE, sv2 = a2 * SCALE;
#pragma unroll
            for (int cy = 0; cy < 2; ++cy) {
#pragma unroll
                for (int cx = 0; cx < 2; ++cx) {
                    float xi = x0 + (float)cx;
                    float yi = y0 + (float)cy;
                    int lx = (int)xi - tx;
                    int ly = (int)yi - ty;
                    if ((unsigned)lx >= (unsigned)TS || (unsigned)ly >= (unsigned)TS) continue;
                    // weight arithmetic identical to reference (hole mask!)
                    float w = (1.f - fabsf(X - xi)) * (1.f - fabsf(Y - yi));
                    if (w == 0.f) continue;          // exact: contributes nothing
                    int c = ly * TS + lx;
                    atomicAdd(&s_acc[0][c], __float2int_rn(sv0 * w));
                    atomicAdd(&s_acc[1][c], __float2int_rn(sv1 * w));
                    atomicAdd(&s_acc[2][c], __float2int_rn(sv2 * w));
                    s_flag[c] = 1;                   // idempotent, race-safe
                }
            }
        }
        i = ni;
        fA = fB; a0 = b0; a1 = b1; a2 = b2; axp = bxp; ayp = byp; avalid = bvalid;
    }
    __syncthreads();

    float* accb = acc + (size_t)b * Cn * HW;
    float* wb   = wacc + (size_t)b * HW;
    for (int i2 = threadIdx.x; i2 < TS * TS; i2 += 1024) {
        int ly = i2 >> 6, lx = i2 & 63;
        int p = ((ty + ly) << 10) + tx + lx;
        accb[p]          = (float)s_acc[0][i2] * INVSC;
        accb[HW + p]     = (float)s_acc[1][i2] * INVSC;
        accb[2 * HW + p] = (float)s_acc[2][i2] * INVSC;
        wb[p]            = s_flag[i2] ? 1.0f : 0.0f;
    }
}

// ------- fallback: the rare |flow|>FMAX pixels, scattered atomics -------
// runs AFTER owner flush (stream-ordered); planes are float by then, and
// wacc += w preserves the !=0 hole-mask semantics.
__global__ __launch_bounds__(BLK) void splat_fallback(
    const float* __restrict__ im0, const float* __restrict__ flow,
    float* __restrict__ acc, float* __restrict__ wacc)
{
    int idx = blockIdx.x * BLK + threadIdx.x;
    if (idx >= BHW) return;
    float2 f = reinterpret_cast<const float2*>(flow)[idx];
    if (fabsf(f.x) <= FMAX && fabsf(f.y) <= FMAX) return;  // owner handled it

    int b = idx >> 20;
    int p = idx & (HW - 1);
    int y = p >> 10;
    int x = p & (Wn - 1);
    float X = (float)x + f.x;
    float Y = (float)y + f.y;
    float x0 = floorf(X), y0 = floorf(Y);
    float v0 = im0[(b * Cn + 0) * HW + p];
    float v1 = im0[(b * Cn + 1) * HW + p];
    float v2 = im0[(b * Cn + 2) * HW + p];
#pragma unroll
    for (int cy = 0; cy < 2; ++cy) {
#pragma unroll
        for (int cx = 0; cx < 2; ++cx) {
            float xi = x0 + (float)cx;
            float yi = y0 + (float)cy;
            if (xi < 0.f || xi > (float)(Wn - 1) ||
                yi < 0.f || yi > (float)(Hn - 1)) continue;
            float w = (1.f - fabsf(X - xi)) * (1.f - fabsf(Y - yi));
            int di = (int)yi * Wn + (int)xi;
            atomicAdd(&wacc[b * HW + di], w);
            atomicAdd(&acc[(b * Cn + 0) * HW + di], v0 * w);
            atomicAdd(&acc[(b * Cn + 1) * HW + di], v1 * w);
            atomicAdd(&acc[(b * Cn + 2) * HW + di], v2 * w);
        }
    }
}

// ------- infill iteration: dst = where(hole, gather(src,flowback), src) -----
__global__ __launch_bounds__(BLK) void infill_kernel(
    const float* __restrict__ src, const float* __restrict__ wacc,
    const float* __restrict__ flowback, float* __restrict__ dst,
    const int* __restrict__ n_iter, int iter)
{
    int n = *n_iter; if (n > MAX_ITERS) n = MAX_ITERS;
    if (iter >= n) return;

    int idx = blockIdx.x * BLK + threadIdx.x;
    if (idx >= BHW) return;
    int b = idx >> 20;
    int p = idx & (HW - 1);

    const float* sb = src + (size_t)b * Cn * HW;
    float o0, o1, o2;
    float wv = wacc[idx];
    if (wv != 0.f) {
        o0 = sb[p];
        o1 = sb[HW + p];
        o2 = sb[2 * HW + p];
    } else {
        int y = p >> 10, x = p & (Wn - 1);
        float2 f = reinterpret_cast<const float2*>(flowback)[idx];
        float X = (float)x + f.x;
        float Y = (float)y + f.y;
        float x0 = floorf(X), y0 = floorf(Y);
        o0 = o1 = o2 = 0.f;
#pragma unroll
        for (int cy = 0; cy < 2; ++cy) {
#pragma unroll
            for (int cx = 0; cx < 2; ++cx) {
                float xi = x0 + (float)cx;
                float yi = y0 + (float)cy;
                if (xi < 0.f || xi > (float)(Wn - 1) ||
                    yi < 0.f || yi > (float)(Hn - 1)) continue;
                float w = (1.f - fabsf(X - xi)) * (1.f - fabsf(Y - yi));
                int gi = (int)yi * Wn + (int)xi;
                o0 += sb[gi] * w;
                o1 += sb[HW + gi] * w;
                o2 += sb[2 * HW + gi] * w;
            }
        }
    }
    float* db = dst + (size_t)b * Cn * HW;
    db[p]          = o0;
    db[HW + p]     = o1;
    db[2 * HW + p] = o2;
}

// ------- if iteration count even (incl. 0), result sits in acc: copy out -----
__global__ __launch_bounds__(BLK) void copy_even_kernel(
    const float* __restrict__ A, float* __restrict__ dst,
    const int* __restrict__ n_iter)
{
    int n = *n_iter; if (n > MAX_ITERS) n = MAX_ITERS;
    if (n & 1) return;   // odd: result already in dst
    int i = blockIdx.x * BLK + threadIdx.x;
    if (i < BCHW) dst[i] = A[i];
}

extern "C" void kernel_launch(void* const* d_in, const int* in_sizes, int n_in,
                              void* d_out, int out_size, void* d_ws, size_t ws_size,
                              hipStream_t stream)
{
    const float* im0      = (const float*)d_in[0];
    const float* flow     = (const float*)d_in[1];
    const float* flowback = (const float*)d_in[2];
    const int*   n_iter   = (const int*)d_in[3];
    float* out  = (float*)d_out;
    float* acc  = (float*)d_ws;          // BCHW floats
    float* wacc = acc + BCHW;            // BHW floats

    // owner splat writes every acc/wacc element -> no memset needed
    int grid_owner = Bn * 256;           // 16x16 tiles of 64x64 per batch
    splat_owner<<<grid_owner, 1024, 0, stream>>>(im0, flow, acc, wacc);

    int grid = (BHW + BLK - 1) / BLK;
    splat_fallback<<<grid, BLK, 0, stream>>>(im0, flow, acc, wacc);

    // ping-pong: iter 0: acc->out, iter 1: out->acc, ...
    for (int i = 0; i < MAX_ITERS; ++i) {
        const float* s = (i % 2 == 0) ? acc : out;
        float*       d = (i % 2 == 0) ? out : acc;
        infill_kernel<<<grid, BLK, 0, stream>>>(s, wacc, flowback, d, n_iter, i);
    }

    int grid2 = (BCHW + BLK - 1) / BLK;
    copy_even_kernel<<<grid2, BLK, 0, stream>>>(acc, out, n_iter);
}

// Round 5
// 129.881 us; speedup vs baseline: 3.3094x; 1.0721x over previous
//
#include <hip/hip_runtime.h>

#define BLK 256

constexpr int Bn = 4, Cn = 3, Hn = 1024, Wn = 1024;
constexpr int HW   = Hn * Wn;        // 1<<20
constexpr int BHW  = Bn * HW;        // 4,194,304
constexpr int BCHW = Bn * Cn * HW;   // 12,582,912
constexpr int MAX_ITERS = 4;

// dest-tile ownership splat
constexpr int TS  = 64;              // dest tile side
constexpr int Mg  = 24;              // source window margin
constexpr int WND = TS + 2 * Mg;     // 112
constexpr int NW  = WND * WND;       // 12544
constexpr float FMAX = 23.0f;        // = Mg-1; owner handles |f|<=FMAX exactly

// fixed-point accumulation (R4: i32 ds_add is banked-fast vs serialized f32)
constexpr float SCALE = 2097152.0f;        // 2^21
constexpr float INVSC = 4.76837158203125e-07f;  // 2^-21 exact

// stage the 4 loads for window coords (WY,WX) if PRED
#define STAGE(PRED, WY, WX, F, V0, V1, V2, PX, PY, VAL)                       \
    {   VAL = false;                                                          \
        if (PRED) {                                                           \
            PY = ty - Mg + (WY);                                              \
            PX = tx - Mg + (WX);                                              \
            if ((unsigned)PY < (unsigned)Hn && (unsigned)PX < (unsigned)Wn) { \
                int p_ = (PY << 10) + PX;                                     \
                F  = flb[p_];                                                 \
                V0 = imb[p_];                                                 \
                V1 = imb[HW + p_];                                            \
                V2 = imb[2 * HW + p_];                                        \
                VAL = true;                                                   \
            }                                                                 \
        }                                                                     \
    }

__global__ __launch_bounds__(1024, 8) void splat_owner(
    const float* __restrict__ im0, const float* __restrict__ flow,
    float* __restrict__ acc, float* __restrict__ wacc)
{
    __shared__ int s_acc[3][TS * TS];   // fixed-point channel accumulators
    __shared__ int s_flag[TS * TS];     // 1 iff any event with w != 0
    const int bid  = blockIdx.x;
    const int b    = bid >> 8;        // 256 tiles per batch (16x16)
    const int tile = bid & 255;
    const int ty   = (tile >> 4) * TS;
    const int tx   = (tile & 15) * TS;

    for (int i = threadIdx.x; i < TS * TS; i += 1024) {
        s_acc[0][i] = 0; s_acc[1][i] = 0; s_acc[2][i] = 0; s_flag[i] = 0;
    }
    __syncthreads();

    const float*  imb = im0 + (size_t)b * Cn * HW;
    const float2* flb = reinterpret_cast<const float2*>(flow) + (size_t)b * HW;

    int i  = threadIdx.x;
    int wy = i / WND, wx = i - wy * WND;      // one-time div (i < 1024)
    float2 fA; float a0, a1, a2; int axp, ayp; bool avalid;
    STAGE(true, wy, wx, fA, a0, a1, a2, axp, ayp, avalid);

    while (i < NW) {
        int ni  = i + 1024;
        int nwx = wx + (1024 % WND);          // +16
        int nwy = wy + (1024 / WND);          // +9
        if (nwx >= WND) { nwx -= WND; ++nwy; }
        // prefetch next iteration's 4 loads before touching this one's data
        float2 fB; float b0, b1, b2; int bxp, byp; bool bvalid;
        STAGE(ni < NW, nwy, nwx, fB, b0, b1, b2, bxp, byp, bvalid);

        if (avalid && fabsf(fA.x) <= FMAX && fabsf(fA.y) <= FMAX) {
            float X = (float)axp + fA.x;
            float Y = (float)ayp + fA.y;
            float x0 = floorf(X), y0 = floorf(Y);
            // shared bilinear factors; per-corner product identical to ref
            float wx0 = 1.f - fabsf(X - x0);
            float wx1 = 1.f - fabsf(X - (x0 + 1.f));
            float wy0 = 1.f - fabsf(Y - y0);
            float wy1 = 1.f - fabsf(Y - (y0 + 1.f));
            int lx0 = (int)x0 - tx;
            int ly0 = (int)y0 - ty;
            float sv0 = a0 * SCALE, sv1 = a1 * SCALE, sv2 = a2 * SCALE;
#pragma unroll
            for (int cy = 0; cy < 2; ++cy) {
                int ly = ly0 + cy;
                if ((unsigned)ly >= (unsigned)TS) continue;
                float wyf = cy ? wy1 : wy0;
#pragma unroll
                for (int cx = 0; cx < 2; ++cx) {
                    int lx = lx0 + cx;
                    if ((unsigned)lx >= (unsigned)TS) continue;
                    float w = (cx ? wx1 : wx0) * wyf;
                    if (w == 0.f) continue;          // exact: contributes nothing
                    int c = ly * TS + lx;
                    atomicAdd(&s_acc[0][c], __float2int_rn(sv0 * w));
                    atomicAdd(&s_acc[1][c], __float2int_rn(sv1 * w));
                    atomicAdd(&s_acc[2][c], __float2int_rn(sv2 * w));
                    s_flag[c] = 1;                   // idempotent, race-safe
                }
            }
        }
        i = ni; wy = nwy; wx = nwx;
        fA = fB; a0 = b0; a1 = b1; a2 = b2; axp = bxp; ayp = byp; avalid = bvalid;
    }
    __syncthreads();

    float* accb = acc + (size_t)b * Cn * HW;
    float* wb   = wacc + (size_t)b * HW;
    for (int i2 = threadIdx.x; i2 < TS * TS; i2 += 1024) {
        int ly = i2 >> 6, lx = i2 & 63;
        int p = ((ty + ly) << 10) + tx + lx;
        accb[p]          = (float)s_acc[0][i2] * INVSC;
        accb[HW + p]     = (float)s_acc[1][i2] * INVSC;
        accb[2 * HW + p] = (float)s_acc[2][i2] * INVSC;
        wb[p]            = s_flag[i2] ? 1.0f : 0.0f;
    }
}

// ------- fallback: the rare |flow|>FMAX pixels, scattered atomics -------
// runs AFTER owner flush (stream-ordered); planes are float by then, and
// wacc += w preserves the !=0 hole-mask semantics. 2 px/thread, float4 flow.
__global__ __launch_bounds__(BLK) void splat_fallback(
    const float* __restrict__ im0, const float* __restrict__ flow,
    float* __restrict__ acc, float* __restrict__ wacc)
{
    int t = blockIdx.x * BLK + threadIdx.x;
    if (t >= BHW / 2) return;
    int idx0 = t * 2;
    float4 ff = *reinterpret_cast<const float4*>(&flow[(size_t)idx0 * 2]);

#pragma unroll
    for (int k = 0; k < 2; ++k) {
        float fx = k ? ff.z : ff.x;
        float fy = k ? ff.w : ff.y;
        if (fabsf(fx) <= FMAX && fabsf(fy) <= FMAX) continue;  // owner handled
        int idx = idx0 + k;
        int b = idx >> 20;
        int p = idx & (HW - 1);
        int y = p >> 10;
        int x = p & (Wn - 1);
        float X = (float)x + fx;
        float Y = (float)y + fy;
        float x0 = floorf(X), y0 = floorf(Y);
        float v0 = im0[(b * Cn + 0) * HW + p];
        float v1 = im0[(b * Cn + 1) * HW + p];
        float v2 = im0[(b * Cn + 2) * HW + p];
#pragma unroll
        for (int cy = 0; cy < 2; ++cy) {
#pragma unroll
            for (int cx = 0; cx < 2; ++cx) {
                float xi = x0 + (float)cx;
                float yi = y0 + (float)cy;
                if (xi < 0.f || xi > (float)(Wn - 1) ||
                    yi < 0.f || yi > (float)(Hn - 1)) continue;
                float w = (1.f - fabsf(X - xi)) * (1.f - fabsf(Y - yi));
                int di = (int)yi * Wn + (int)xi;
                atomicAdd(&wacc[b * HW + di], w);
                atomicAdd(&acc[(b * Cn + 0) * HW + di], v0 * w);
                atomicAdd(&acc[(b * Cn + 1) * HW + di], v1 * w);
                atomicAdd(&acc[(b * Cn + 2) * HW + di], v2 * w);
            }
        }
    }
}

// ------- infill iteration: dst = where(hole, gather(src,flowback), src) -----
// 4 px/thread float4; gather only at holes (~2-3%).
__global__ __launch_bounds__(BLK) void infill_kernel(
    const float* __restrict__ src, const float* __restrict__ wacc,
    const float* __restrict__ flowback, float* __restrict__ dst,
    const int* __restrict__ n_iter, int iter)
{
    int n = *n_iter; if (n > MAX_ITERS) n = MAX_ITERS;
    if (iter >= n) return;

    int q = blockIdx.x * BLK + threadIdx.x;
    if (q >= BHW / 4) return;
    int idx = q * 4;
    int b = idx >> 20;
    int p = idx & (HW - 1);

    const float* sb = src + (size_t)b * Cn * HW;
    float4 wv = *reinterpret_cast<const float4*>(&wacc[idx]);
    float4 o0 = *reinterpret_cast<const float4*>(&sb[p]);
    float4 o1 = *reinterpret_cast<const float4*>(&sb[HW + p]);
    float4 o2 = *reinterpret_cast<const float4*>(&sb[2 * HW + p]);

    if (wv.x == 0.f || wv.y == 0.f || wv.z == 0.f || wv.w == 0.f) {
        int y = p >> 10, x = p & (Wn - 1);
        const float2* fbp = reinterpret_cast<const float2*>(flowback) + idx;
        float* o0a = reinterpret_cast<float*>(&o0);
        float* o1a = reinterpret_cast<float*>(&o1);
        float* o2a = reinterpret_cast<float*>(&o2);
        const float* wva = reinterpret_cast<const float*>(&wv);
#pragma unroll
        for (int k = 0; k < 4; ++k) {
            if (wva[k] != 0.f) continue;
            float2 f = fbp[k];
            float X = (float)(x + k) + f.x;
            float Y = (float)y + f.y;
            float x0 = floorf(X), y0 = floorf(Y);
            float g0 = 0.f, g1 = 0.f, g2 = 0.f;
#pragma unroll
            for (int cy = 0; cy < 2; ++cy) {
#pragma unroll
                for (int cx = 0; cx < 2; ++cx) {
                    float xi = x0 + (float)cx;
                    float yi = y0 + (float)cy;
                    if (xi < 0.f || xi > (float)(Wn - 1) ||
                        yi < 0.f || yi > (float)(Hn - 1)) continue;
                    float w = (1.f - fabsf(X - xi)) * (1.f - fabsf(Y - yi));
                    int gi = (int)yi * Wn + (int)xi;
                    g0 += sb[gi] * w;
                    g1 += sb[HW + gi] * w;
                    g2 += sb[2 * HW + gi] * w;
                }
            }
            o0a[k] = g0; o1a[k] = g1; o2a[k] = g2;
        }
    }
    float* db = dst + (size_t)b * Cn * HW;
    *reinterpret_cast<float4*>(&db[p])          = o0;
    *reinterpret_cast<float4*>(&db[HW + p])     = o1;
    *reinterpret_cast<float4*>(&db[2 * HW + p]) = o2;
}

// ------- if iteration count even (incl. 0), result sits in acc: copy out -----
__global__ __launch_bounds__(BLK) void copy_even_kernel(
    const float* __restrict__ A, float* __restrict__ dst,
    const int* __restrict__ n_iter)
{
    int n = *n_iter; if (n > MAX_ITERS) n = MAX_ITERS;
    if (n & 1) return;   // odd: result already in dst
    int i = (blockIdx.x * BLK + threadIdx.x) * 4;
    if (i < BCHW)
        *reinterpret_cast<float4*>(&dst[i]) =
            *reinterpret_cast<const float4*>(&A[i]);
}

extern "C" void kernel_launch(void* const* d_in, const int* in_sizes, int n_in,
                              void* d_out, int out_size, void* d_ws, size_t ws_size,
                              hipStream_t stream)
{
    const float* im0      = (const float*)d_in[0];
    const float* flow     = (const float*)d_in[1];
    const float* flowback = (const float*)d_in[2];
    const int*   n_iter   = (const int*)d_in[3];
    float* out  = (float*)d_out;
    float* acc  = (float*)d_ws;          // BCHW floats
    float* wacc = acc + BCHW;            // BHW floats

    // owner splat writes every acc/wacc element -> no memset needed
    int grid_owner = Bn * 256;           // 16x16 tiles of 64x64 per batch
    splat_owner<<<grid_owner, 1024, 0, stream>>>(im0, flow, acc, wacc);

    splat_fallback<<<(BHW / 2) / BLK, BLK, 0, stream>>>(im0, flow, acc, wacc);

    // ping-pong: iter 0: acc->out, iter 1: out->acc, ...
    int grid_inf = (BHW / 4) / BLK;
    for (int i = 0; i < MAX_ITERS; ++i) {
        const float* s = (i % 2 == 0) ? acc : out;
        float*       d = (i % 2 == 0) ? out : acc;
        infill_kernel<<<grid_inf, BLK, 0, stream>>>(s, wacc, flowback, d, n_iter, i);
    }

    copy_even_kernel<<<(BCHW / 4) / BLK, BLK, 0, stream>>>(acc, out, n_iter);
}

// Round 6
// 109.493 us; speedup vs baseline: 3.9256x; 1.1862x over previous
//
#include <hip/hip_runtime.h>

#define BLK 256

constexpr int Bn = 4, Cn = 3, Hn = 1024, Wn = 1024;
constexpr int HW   = Hn * Wn;        // 1<<20
constexpr int BHW  = Bn * HW;        // 4,194,304
constexpr int BCHW = Bn * Cn * HW;   // 12,582,912
constexpr int MAX_ITERS = 4;

// dest-tile ownership splat
constexpr int TS  = 64;              // dest tile side
constexpr int Mg  = 24;              // source window margin
constexpr int WND = TS + 2 * Mg;     // 112
constexpr int NW  = WND * WND;       // 12544
constexpr float FMAX = 23.0f;        // = Mg-1; owner handles |f|<=FMAX exactly

// fixed-point accumulation (R4: i32 ds_add is banked-fast vs serialized f32)
constexpr float SCALE = 2097152.0f;        // 2^21
constexpr float INVSC = 4.76837158203125e-07f;  // 2^-21 exact

// flow-only prefetch; sentinel 1e9 fails the FMAX test for out-of-image px
#define STAGEF(PRED, WY, WX, F, PX, PY)                                       \
    {   PY = ty - Mg + (WY);                                                  \
        PX = tx - Mg + (WX);                                                  \
        F = make_float2(1e9f, 1e9f);                                          \
        if ((PRED) && (unsigned)PY < (unsigned)Hn &&                          \
            (unsigned)PX < (unsigned)Wn)                                      \
            F = flb[(PY << 10) + PX];                                         \
    }

__global__ __launch_bounds__(1024, 8) void splat_owner(
    const float* __restrict__ im0, const float* __restrict__ flow,
    float* __restrict__ acc, unsigned* __restrict__ wm)
{
    __shared__ int s_acc[3][TS * TS];   // fixed-point channel accumulators
    __shared__ int s_flag[TS * TS];     // 1 iff any event with w != 0
    // XCD-bijective swizzle (1024 blocks, 8 XCDs): contiguous tile rows/XCD
    const int bid  = ((blockIdx.x & 7) << 7) | (blockIdx.x >> 3);
    const int b    = bid >> 8;        // 256 tiles per batch (16x16)
    const int tile = bid & 255;
    const int ty   = (tile >> 4) * TS;
    const int tx   = (tile & 15) * TS;

    for (int i = threadIdx.x; i < TS * TS; i += 1024) {
        s_acc[0][i] = 0; s_acc[1][i] = 0; s_acc[2][i] = 0; s_flag[i] = 0;
    }
    __syncthreads();

    const float*  imb = im0 + (size_t)b * Cn * HW;
    const float2* flb = reinterpret_cast<const float2*>(flow) + (size_t)b * HW;

    int i  = threadIdx.x;
    int wy = i / WND, wx = i - wy * WND;      // one-time div (i < 1024)
    int axp, ayp; float2 fA;
    STAGEF(true, wy, wx, fA, axp, ayp);

    while (i < NW) {
        int ni  = i + 1024;
        int nwx = wx + (1024 % WND);          // +16
        int nwy = wy + (1024 / WND);          // +9
        if (nwx >= WND) { nwx -= WND; ++nwy; }
        // prefetch next visit's flow before processing this one
        int bxp, byp; float2 fB;
        STAGEF(ni < NW, nwy, nwx, fB, bxp, byp);

        if (fabsf(fA.x) <= FMAX && fabsf(fA.y) <= FMAX) {
            float X = (float)axp + fA.x;
            float Y = (float)ayp + fA.y;
            float x0 = floorf(X), y0 = floorf(Y);
            int lx0 = (int)x0 - tx;
            int ly0 = (int)y0 - ty;
            // box reject: any of the 2x2 corners inside this tile?
            if (lx0 >= -1 && lx0 < TS && ly0 >= -1 && ly0 < TS) {
                // shared bilinear factors; per-corner product identical to ref
                float wxa = 1.f - fabsf(X - x0);
                float wxb = 1.f - fabsf(X - (x0 + 1.f));
                float wya = 1.f - fabsf(Y - y0);
                float wyb = 1.f - fabsf(Y - (y0 + 1.f));
                float w00 = wxa * wya, w01 = wxb * wya;
                float w10 = wxa * wyb, w11 = wxb * wyb;
                bool i00 = (unsigned)ly0     < (unsigned)TS && (unsigned)lx0     < (unsigned)TS && w00 != 0.f;
                bool i01 = (unsigned)ly0     < (unsigned)TS && (unsigned)(lx0+1) < (unsigned)TS && w01 != 0.f;
                bool i10 = (unsigned)(ly0+1) < (unsigned)TS && (unsigned)lx0     < (unsigned)TS && w10 != 0.f;
                bool i11 = (unsigned)(ly0+1) < (unsigned)TS && (unsigned)(lx0+1) < (unsigned)TS && w11 != 0.f;
                if (i00 | i01 | i10 | i11) {
                    // im0 loads only when this pixel actually contributes
                    int p_ = (ayp << 10) + axp;
                    float sv0 = imb[p_]          * SCALE;
                    float sv1 = imb[HW + p_]     * SCALE;
                    float sv2 = imb[2 * HW + p_] * SCALE;
                    if (i00) {
                        int c = ly0 * TS + lx0;
                        atomicAdd(&s_acc[0][c], __float2int_rz(sv0 * w00));
                        atomicAdd(&s_acc[1][c], __float2int_rz(sv1 * w00));
                        atomicAdd(&s_acc[2][c], __float2int_rz(sv2 * w00));
                        s_flag[c] = 1;
                    }
                    if (i01) {
                        int c = ly0 * TS + lx0 + 1;
                        atomicAdd(&s_acc[0][c], __float2int_rz(sv0 * w01));
                        atomicAdd(&s_acc[1][c], __float2int_rz(sv1 * w01));
                        atomicAdd(&s_acc[2][c], __float2int_rz(sv2 * w01));
                        s_flag[c] = 1;
                    }
                    if (i10) {
                        int c = (ly0 + 1) * TS + lx0;
                        atomicAdd(&s_acc[0][c], __float2int_rz(sv0 * w10));
                        atomicAdd(&s_acc[1][c], __float2int_rz(sv1 * w10));
                        atomicAdd(&s_acc[2][c], __float2int_rz(sv2 * w10));
                        s_flag[c] = 1;
                    }
                    if (i11) {
                        int c = (ly0 + 1) * TS + lx0 + 1;
                        atomicAdd(&s_acc[0][c], __float2int_rz(sv0 * w11));
                        atomicAdd(&s_acc[1][c], __float2int_rz(sv1 * w11));
                        atomicAdd(&s_acc[2][c], __float2int_rz(sv2 * w11));
                        s_flag[c] = 1;
                    }
                }
            }
        }
        i = ni; wy = nwy; wx = nwx;
        fA = fB; axp = bxp; ayp = byp;
    }
    __syncthreads();

    float* accb = acc + (size_t)b * Cn * HW;
    const int lane = threadIdx.x & 63;
    for (int i2 = threadIdx.x; i2 < TS * TS; i2 += 1024) {
        int row = i2 >> 6;                    // wave <-> one 64-px tile row
        int p = ((ty + row) << 10) + tx + (i2 & 63);
        accb[p]          = (float)s_acc[0][i2] * INVSC;
        accb[HW + p]     = (float)s_acc[1][i2] * INVSC;
        accb[2 * HW + p] = (float)s_acc[2][i2] * INVSC;
        unsigned long long m = __ballot(s_flag[i2] != 0);
        int wbase = (b * HW + ((ty + row) << 10) + tx) >> 5;
        if (lane == 0)  wm[wbase]     = (unsigned)m;
        if (lane == 32) wm[wbase + 1] = (unsigned)(m >> 32);
    }
}

// ------- fallback: the rare |flow|>FMAX pixels, scattered atomics -------
// runs AFTER owner flush (stream-ordered); planes are float by then; mask bit
// OR preserves the !=0 hole semantics (only set when w != 0).
__global__ __launch_bounds__(BLK) void splat_fallback(
    const float* __restrict__ im0, const float* __restrict__ flow,
    float* __restrict__ acc, unsigned* __restrict__ wm)
{
    int t = blockIdx.x * BLK + threadIdx.x;
    if (t >= BHW / 2) return;
    int idx0 = t * 2;
    float4 ff = *reinterpret_cast<const float4*>(&flow[(size_t)idx0 * 2]);

#pragma unroll
    for (int k = 0; k < 2; ++k) {
        float fx = k ? ff.z : ff.x;
        float fy = k ? ff.w : ff.y;
        if (fabsf(fx) <= FMAX && fabsf(fy) <= FMAX) continue;  // owner handled
        int idx = idx0 + k;
        int b = idx >> 20;
        int p = idx & (HW - 1);
        int y = p >> 10;
        int x = p & (Wn - 1);
        float X = (float)x + fx;
        float Y = (float)y + fy;
        float x0 = floorf(X), y0 = floorf(Y);
        float v0 = im0[(b * Cn + 0) * HW + p];
        float v1 = im0[(b * Cn + 1) * HW + p];
        float v2 = im0[(b * Cn + 2) * HW + p];
#pragma unroll
        for (int cy = 0; cy < 2; ++cy) {
#pragma unroll
            for (int cx = 0; cx < 2; ++cx) {
                float xi = x0 + (float)cx;
                float yi = y0 + (float)cy;
                if (xi < 0.f || xi > (float)(Wn - 1) ||
                    yi < 0.f || yi > (float)(Hn - 1)) continue;
                float w = (1.f - fabsf(X - xi)) * (1.f - fabsf(Y - yi));
                if (w == 0.f) continue;
                int di = (int)yi * Wn + (int)xi;
                int gi = b * HW + di;
                atomicOr(&wm[gi >> 5], 1u << (gi & 31));
                atomicAdd(&acc[(b * Cn + 0) * HW + di], v0 * w);
                atomicAdd(&acc[(b * Cn + 1) * HW + di], v1 * w);
                atomicAdd(&acc[(b * Cn + 2) * HW + di], v2 * w);
            }
        }
    }
}

// ------- infill iteration: dst = where(hole, gather(src,flowback), src) -----
// 4 px/thread float4, grid-stride; gather only at holes (~2-3%).
__global__ __launch_bounds__(BLK) void infill_kernel(
    const float* __restrict__ src, const unsigned* __restrict__ wm,
    const float* __restrict__ flowback, float* __restrict__ dst,
    const int* __restrict__ n_iter, int iter)
{
    int n = *n_iter; if (n > MAX_ITERS) n = MAX_ITERS;
    if (iter >= n) return;

    for (int q = blockIdx.x * BLK + threadIdx.x; q < BHW / 4;
         q += gridDim.x * BLK) {
        int idx = q * 4;
        int b = idx >> 20;
        int p = idx & (HW - 1);

        const float* sb = src + (size_t)b * Cn * HW;
        unsigned nib = (wm[idx >> 5] >> (idx & 31)) & 0xFu;
        float4 o0 = *reinterpret_cast<const float4*>(&sb[p]);
        float4 o1 = *reinterpret_cast<const float4*>(&sb[HW + p]);
        float4 o2 = *reinterpret_cast<const float4*>(&sb[2 * HW + p]);

        if (nib != 0xFu) {
            int y = p >> 10, x = p & (Wn - 1);
            const float2* fbp = reinterpret_cast<const float2*>(flowback) + idx;
            float* o0a = reinterpret_cast<float*>(&o0);
            float* o1a = reinterpret_cast<float*>(&o1);
            float* o2a = reinterpret_cast<float*>(&o2);
#pragma unroll
            for (int k = 0; k < 4; ++k) {
                if ((nib >> k) & 1u) continue;
                float2 f = fbp[k];
                float X = (float)(x + k) + f.x;
                float Y = (float)y + f.y;
                float x0 = floorf(X), y0 = floorf(Y);
                float g0 = 0.f, g1 = 0.f, g2 = 0.f;
#pragma unroll
                for (int cy = 0; cy < 2; ++cy) {
#pragma unroll
                    for (int cx = 0; cx < 2; ++cx) {
                        float xi = x0 + (float)cx;
                        float yi = y0 + (float)cy;
                        if (xi < 0.f || xi > (float)(Wn - 1) ||
                            yi < 0.f || yi > (float)(Hn - 1)) continue;
                        float w = (1.f - fabsf(X - xi)) * (1.f - fabsf(Y - yi));
                        int gi = (int)yi * Wn + (int)xi;
                        g0 += sb[gi] * w;
                        g1 += sb[HW + gi] * w;
                        g2 += sb[2 * HW + gi] * w;
                    }
                }
                o0a[k] = g0; o1a[k] = g1; o2a[k] = g2;
            }
        }
        float* db = dst + (size_t)b * Cn * HW;
        *reinterpret_cast<float4*>(&db[p])          = o0;
        *reinterpret_cast<float4*>(&db[HW + p])     = o1;
        *reinterpret_cast<float4*>(&db[2 * HW + p]) = o2;
    }
}

// ------- if iteration count even (incl. 0), result sits in acc: copy out -----
__global__ __launch_bounds__(BLK) void copy_even_kernel(
    const float* __restrict__ A, float* __restrict__ dst,
    const int* __restrict__ n_iter)
{
    int n = *n_iter; if (n > MAX_ITERS) n = MAX_ITERS;
    if (n & 1) return;   // odd: result already in dst
    for (int q = blockIdx.x * BLK + threadIdx.x; q < BCHW / 4;
         q += gridDim.x * BLK) {
        int i = q * 4;
        *reinterpret_cast<float4*>(&dst[i]) =
            *reinterpret_cast<const float4*>(&A[i]);
    }
}

extern "C" void kernel_launch(void* const* d_in, const int* in_sizes, int n_in,
                              void* d_out, int out_size, void* d_ws, size_t ws_size,
                              hipStream_t stream)
{
    const float* im0      = (const float*)d_in[0];
    const float* flow     = (const float*)d_in[1];
    const float* flowback = (const float*)d_in[2];
    const int*   n_iter   = (const int*)d_in[3];
    float* out = (float*)d_out;
    float* acc = (float*)d_ws;                       // BCHW floats
    unsigned* wm = (unsigned*)(acc + BCHW);          // BHW/32 mask words

    // owner splat writes every acc element and every mask word -> no memset
    splat_owner<<<Bn * 256, 1024, 0, stream>>>(im0, flow, acc, wm);

    splat_fallback<<<(BHW / 2) / BLK, BLK, 0, stream>>>(im0, flow, acc, wm);

    // ping-pong: iter 0: acc->out, iter 1: out->acc, ...
    for (int i = 0; i < MAX_ITERS; ++i) {
        const float* s = (i % 2 == 0) ? acc : out;
        float*       d = (i % 2 == 0) ? out : acc;
        infill_kernel<<<2048, BLK, 0, stream>>>(s, wm, flowback, d, n_iter, i);
    }

    copy_even_kernel<<<1024, BLK, 0, stream>>>(acc, out, n_iter);
}